// Round 2
// baseline (192.679 us; speedup 1.0000x reference)
//
#include <hip/hip_runtime.h>

// ---------- problem constants ----------
#define BATCH   2
#define SEQ     2048
#define DMODEL  1024
#define NHEAD   16
#define DKH     64
#define MTOT    (BATCH*SEQ)      // 4096 rows for the projection GEMMs
#define KDIM    DMODEL           // 1024 contraction for projections

// ws layout in bf16 elements (total 24M bf16 = 48 MB)
#define XB    0u                     // x bf16            [4096,1024]  4M
#define WQB   (4u*1024u*1024u)       // Wq bf16           [1024,1024]  1M
#define WKB   (5u*1024u*1024u)
#define WVB   (6u*1024u*1024u)
#define WOB   (7u*1024u*1024u)
#define QOFF  (8u*1024u*1024u)       // Q  [B,H,N,dk] (pre-scaled log2e/8) 4M
#define KOFF  (12u*1024u*1024u)      // K  [B,H,N,dk]                  4M
#define VOFF  (16u*1024u*1024u)      // V^T [B,H,dk,N]                 4M
#define OOFF  (20u*1024u*1024u)      // attn out, flat [B,N,D]         4M

typedef __bf16 bf16x8 __attribute__((ext_vector_type(8)));
typedef __bf16 bf16x4 __attribute__((ext_vector_type(4)));
typedef float  f32x4  __attribute__((ext_vector_type(4)));
typedef float  f32x16 __attribute__((ext_vector_type(16)));

// async global->LDS, 16B per lane; LDS dest is wave-uniform base (HW adds lane*16)
__device__ __forceinline__ void async16(const __bf16* g, __bf16* l) {
  __builtin_amdgcn_global_load_lds(
      (const __attribute__((address_space(1))) void*)g,
      (__attribute__((address_space(3))) void*)l, 16, 0, 0);
}

// packed f32x2 -> bf16x2 (dword): lo in low 16 bits (T12 recipe, no builtin)
__device__ __forceinline__ unsigned cvtpk_bf16(float lo, float hi) {
  unsigned r;
  asm("v_cvt_pk_bf16_f32 %0, %1, %2" : "=v"(r) : "v"(lo), "v"(hi));
  return r;
}
// v_permlane32_swap_b32: a.hi32lanes <-> b.lo32lanes
__device__ __forceinline__ void plswap(unsigned& a, unsigned& b) {
  asm("v_permlane32_swap_b32 %0, %1" : "+v"(a), "+v"(b));
}

// ---------------------------------------------------------------------------
// fp32 -> bf16 conversion: blockIdx.y selects tensor (0:x, 1..4:Wq/Wk/Wv/Wo)
// ---------------------------------------------------------------------------
__global__ __launch_bounds__(256) void cvt_fp32_bf16(
    const float* __restrict__ x,  const float* __restrict__ wq,
    const float* __restrict__ wk, const float* __restrict__ wv,
    const float* __restrict__ wo, __bf16* __restrict__ ws)
{
  const float* src; __bf16* dst; int n;
  switch (blockIdx.y) {
    case 0:  src = x;  dst = ws + XB;  n = 4 * 1024 * 1024; break;
    case 1:  src = wq; dst = ws + WQB; n = 1024 * 1024;     break;
    case 2:  src = wk; dst = ws + WKB; n = 1024 * 1024;     break;
    case 3:  src = wv; dst = ws + WVB; n = 1024 * 1024;     break;
    default: src = wo; dst = ws + WOB; n = 1024 * 1024;     break;
  }
  const int i = (blockIdx.x * 256 + threadIdx.x) * 8;
  if (i < n) {
    const float4 a = *(const float4*)(src + i);
    const float4 b = *(const float4*)(src + i + 4);
    bf16x8 o;
    o[0] = (__bf16)a.x; o[1] = (__bf16)a.y; o[2] = (__bf16)a.z; o[3] = (__bf16)a.w;
    o[4] = (__bf16)b.x; o[5] = (__bf16)b.y; o[6] = (__bf16)b.z; o[7] = (__bf16)b.w;
    *(bf16x8*)(dst + i) = o;
  }
}

// ---------------------------------------------------------------------------
// 128x128 NT-GEMM core, BK=32, DOUBLE-BUFFERED (2-phase T3-lite):
// stage tile t+1 into the idle buffer, compute tile t, one drain-barrier per
// tile. LDS: A0[0,4K) B0[4K,8K) A1[8K,12K) B1[12K,16K) bf16 = 32 KB.
// 16B-chunk XOR swizzle: chunk' = chunk ^ (row & 3).
// ---------------------------------------------------------------------------
__device__ __forceinline__ void gemm_stage128(
    const __bf16* __restrict__ A, const __bf16* __restrict__ W,
    int m0, int n0, int kt, __bf16* A_l, __bf16* B_l, int w, int lane)
{
#pragma unroll
  for (int issue = 0; issue < 2; ++issue) {
    const int cbase = issue * 256 + (w << 6);
    const int c     = cbase + lane;
    const int row   = c >> 2;                       // 4 chunks (32 bf16) per row
    const int goff  = ((c & 3) ^ (row & 3)) << 3;   // swizzled source chunk
    async16(A + (size_t)(m0 + row) * KDIM + kt + goff, A_l + cbase * 8);
    async16(W + (size_t)(n0 + row) * KDIM + kt + goff, B_l + cbase * 8);
  }
}

__device__ __forceinline__ void gemm_step128(
    const __bf16* A_lds, const __bf16* B_lds,
    int wr, int wc, int ln15, int quad, f32x4 (&acc)[4][4])
{
  bf16x8 af[4], bfr[4];
#pragma unroll
  for (int i = 0; i < 4; ++i) {
    const int row = wr + i * 16 + ln15;
    af[i] = *(const bf16x8*)&A_lds[row * 32 + ((quad ^ (row & 3)) << 3)];
  }
#pragma unroll
  for (int j = 0; j < 4; ++j) {
    const int row = wc + j * 16 + ln15;
    bfr[j] = *(const bf16x8*)&B_lds[row * 32 + ((quad ^ (row & 3)) << 3)];
  }
#pragma unroll
  for (int i = 0; i < 4; ++i)
#pragma unroll
    for (int j = 0; j < 4; ++j)
      acc[i][j] = __builtin_amdgcn_mfma_f32_16x16x32_bf16(af[i], bfr[j], acc[i][j], 0, 0, 0);
}

__device__ __forceinline__ void gemm128_core(
    const __bf16* __restrict__ A, const __bf16* __restrict__ W,
    int m0, int n0, __bf16* lds, f32x4 (&acc)[4][4])
{
  const int t    = threadIdx.x;
  const int w    = t >> 6;
  const int lane = t & 63;
  const int ln15 = lane & 15;
  const int quad = lane >> 4;
  const int wr   = (w >> 1) << 6;   // wave row offset within 128
  const int wc   = (w & 1) << 6;    // wave col offset within 128

#pragma unroll
  for (int i = 0; i < 4; ++i)
#pragma unroll
    for (int j = 0; j < 4; ++j) acc[i][j] = (f32x4){0.f, 0.f, 0.f, 0.f};

  gemm_stage128(A, W, m0, n0, 0, lds, lds + 4096, w, lane);
  __syncthreads();                          // tile 0 landed

  for (int kt = 0; kt < KDIM; kt += 64) {   // two K-steps per iteration
    gemm_stage128(A, W, m0, n0, kt + 32, lds + 8192, lds + 12288, w, lane);
    gemm_step128(lds, lds + 4096, wr, wc, ln15, quad, acc);
    __syncthreads();                        // drain stage(kt+32); buf0 reads done
    if (kt + 64 < KDIM)
      gemm_stage128(A, W, m0, n0, kt + 64, lds, lds + 4096, w, lane);
    gemm_step128(lds + 8192, lds + 12288, wr, wc, ln15, quad, acc);
    __syncthreads();                        // drain stage(kt+64); buf1 reads done
  }
}

// ---------------------------------------------------------------------------
// Fused QKV projection: z=0 -> Q (scaled log2e/8) [B,H,N,dk]; z=1 -> K;
// z=2 -> V transposed [B,H,dk,N]. Biases fp32. 16B vectorized stores via
// per-wave LDS repack.
// ---------------------------------------------------------------------------
__global__ __launch_bounds__(256) void qkv_gemm(
    const __bf16* __restrict__ X,
    const __bf16* __restrict__ Wq, const float* __restrict__ bq,
    const __bf16* __restrict__ Wk, const float* __restrict__ bk,
    const __bf16* __restrict__ Wv, const float* __restrict__ bv,
    __bf16* __restrict__ ws)
{
  __shared__ __align__(16) __bf16 lds[16384];   // 32 KB (dbuf A/B)

  const int z = blockIdx.z;
  const __bf16* W    = (z == 0) ? Wq : (z == 1) ? Wk : Wv;
  const float*  bias = (z == 0) ? bq : (z == 1) ? bk : bv;
  __bf16* out = ws + ((z == 0) ? QOFF : (z == 1) ? KOFF : VOFF);
  // softmax runs in exp2 domain: fold 1/sqrt(dk) * log2(e) into Q
  const float scale = (z == 0) ? 0.125f * 1.44269504088896f : 1.0f;

  const int m0 = blockIdx.x * 128;
  const int n0 = blockIdx.y * 128;

  f32x4 acc[4][4];
  gemm128_core(X, W, m0, n0, lds, acc);

  const int t = threadIdx.x, w = t >> 6, lane = t & 63;
  const int ln15 = lane & 15, quad = lane >> 4;
  const int wr = (w >> 1) << 6, wc = (w & 1) << 6;

  // bias values for this wave's 64 columns (col = j*16+ln15)
  float bj4[4];
#pragma unroll
  for (int j = 0; j < 4; ++j) bj4[j] = bias[n0 + wc + j * 16 + ln15];

  __syncthreads();                     // all waves done reading K-tiles
  __bf16* scr = lds + (w << 10);       // per-wave 1024-elem scratch (2 KB)

  const int bb = m0 >> 11;             // batch (blocks never straddle)
  const int s_base = (m0 & 2047) + wr;
  const int h = (n0 + wc) >> 6;

  if (z != 2) {
    // ---- Q/K [B,H,N,dk]: row-major scratch [row16][d64], coalesced stores
    const int rdrow = lane & 15, rdseg = lane >> 4;
#pragma unroll
    for (int i = 0; i < 4; ++i) {
#pragma unroll
      for (int j = 0; j < 4; ++j)
#pragma unroll
        for (int rr = 0; rr < 4; ++rr)
          scr[(quad * 4 + rr) * 64 + j * 16 + ln15] =
              (__bf16)((acc[i][j][rr] + bj4[j]) * scale);
      // wave-private scratch: compiler orders via lgkmcnt, no barrier
      bf16x8 v0 = *(const bf16x8*)&scr[rdrow * 64 + rdseg * 16];
      bf16x8 v1 = *(const bf16x8*)&scr[rdrow * 64 + rdseg * 16 + 8];
      const int s = s_base + i * 16 + rdrow;
      __bf16* p = out + (((size_t)(bb * NHEAD + h)) * SEQ + s) * DKH + rdseg * 16;
      *(bf16x8*)p = v0;
      *(bf16x8*)&p[8] = v1;
    }
  } else {
    // ---- V^T [B,H,dk,N]: col-major scratch [d64][row16] does the transpose;
    // each lane then stores 32B contiguous in s.
#pragma unroll
    for (int i = 0; i < 4; ++i) {
#pragma unroll
      for (int j = 0; j < 4; ++j) {
        bf16x4 pk;
#pragma unroll
        for (int rr = 0; rr < 4; ++rr) pk[rr] = (__bf16)(acc[i][j][rr] + bj4[j]);
        *(bf16x4*)&scr[(j * 16 + ln15) * 16 + quad * 4] = pk;
      }
      bf16x8 c0 = *(const bf16x8*)&scr[lane * 16];
      bf16x8 c1 = *(const bf16x8*)&scr[lane * 16 + 8];
      __bf16* p = out + (((size_t)(bb * NHEAD + h)) * DKH + lane) * SEQ
                      + s_base + i * 16;
      *(bf16x8*)p = c0;
      *(bf16x8*)&p[8] = c1;
    }
  }
}

// ---------------------------------------------------------------------------
// Output projection: d_out(fp32) = O[M,K]bf16 @ Wo[N,K]bf16^T + bo(fp32).
// 64x128 tile -> 512 blocks (2/CU). 4 waves, each 64 rows x 32 cols.
// Double-buffered (same 2-phase): LDS A0|B0|A1|B1 = 24 KB.
// ---------------------------------------------------------------------------
__device__ __forceinline__ void out_stage(
    const __bf16* __restrict__ A, const __bf16* __restrict__ Wo,
    int m0, int n0, int kt, __bf16* A_l, __bf16* B_l, int w, int lane)
{
  {  // A: 64 rows x 4 chunks = 256 chunks = 1 issue
    const int c = (w << 6) + lane;
    const int row = c >> 2;
    const int goff = ((c & 3) ^ (row & 3)) << 3;
    async16(A + (size_t)(m0 + row) * KDIM + kt + goff, A_l + c * 8);
  }
#pragma unroll
  for (int issue = 0; issue < 2; ++issue) {  // B: 128 rows x 4 chunks = 2 issues
    const int cbase = issue * 256 + (w << 6);
    const int c = cbase + lane;
    const int row = c >> 2;
    const int goff = ((c & 3) ^ (row & 3)) << 3;
    async16(Wo + (size_t)(n0 + row) * KDIM + kt + goff, B_l + cbase * 8);
  }
}

__device__ __forceinline__ void out_step(
    const __bf16* A_lds, const __bf16* B_lds,
    int w, int ln15, int quad, f32x4 (&acc)[4][2])
{
  bf16x8 af[4], bfr[2];
#pragma unroll
  for (int i = 0; i < 4; ++i) {
    const int row = i * 16 + ln15;
    af[i] = *(const bf16x8*)&A_lds[row * 32 + ((quad ^ (row & 3)) << 3)];
  }
#pragma unroll
  for (int j = 0; j < 2; ++j) {
    const int row = (w << 5) + j * 16 + ln15;
    bfr[j] = *(const bf16x8*)&B_lds[row * 32 + ((quad ^ (row & 3)) << 3)];
  }
#pragma unroll
  for (int i = 0; i < 4; ++i)
#pragma unroll
    for (int j = 0; j < 2; ++j)
      acc[i][j] = __builtin_amdgcn_mfma_f32_16x16x32_bf16(af[i], bfr[j], acc[i][j], 0, 0, 0);
}

__global__ __launch_bounds__(256) void out_gemm(
    const __bf16* __restrict__ A, const __bf16* __restrict__ Wo,
    const float* __restrict__ bo, float* __restrict__ out)
{
  __shared__ __align__(16) __bf16 lds[12288];   // 24 KB dbuf
  __bf16* A0 = lds;            // [0,2048)
  __bf16* B0 = lds + 2048;     // [2048,6144)
  __bf16* A1 = lds + 6144;     // [6144,8192)
  __bf16* B1 = lds + 8192;     // [8192,12288)

  const int m0 = blockIdx.x * 64;
  const int n0 = blockIdx.y * 128;

  const int t = threadIdx.x, w = t >> 6, lane = t & 63;
  const int ln15 = lane & 15, quad = lane >> 4;

  f32x4 acc[4][2];
#pragma unroll
  for (int i = 0; i < 4; ++i)
#pragma unroll
    for (int j = 0; j < 2; ++j) acc[i][j] = (f32x4){0.f, 0.f, 0.f, 0.f};

  out_stage(A, Wo, m0, n0, 0, A0, B0, w, lane);
  __syncthreads();

  for (int kt = 0; kt < KDIM; kt += 64) {
    out_stage(A, Wo, m0, n0, kt + 32, A1, B1, w, lane);
    out_step(A0, B0, w, ln15, quad, acc);
    __syncthreads();
    if (kt + 64 < KDIM)
      out_stage(A, Wo, m0, n0, kt + 64, A0, B0, w, lane);
    out_step(A1, B1, w, ln15, quad, acc);
    __syncthreads();
  }

  float bj2[2];
#pragma unroll
  for (int j = 0; j < 2; ++j) bj2[j] = bo[n0 + (w << 5) + j * 16 + ln15];

  float* scrf = (float*)lds + (w << 9);     // per-wave 512-float scratch (2 KB)

  const int rdrow = lane & 15, rdseg = lane >> 4;
#pragma unroll
  for (int i = 0; i < 4; ++i) {
#pragma unroll
    for (int j = 0; j < 2; ++j) {
      f32x4 v;
#pragma unroll
      for (int rr = 0; rr < 4; ++rr) v[rr] = acc[i][j][rr] + bj2[j];
      *(f32x4*)&scrf[(j * 16 + ln15) * 16 + quad * 4] = v;   // col-major
    }
    const int m = m0 + i * 16 + rdrow;
    float* p = out + (size_t)m * DMODEL + n0 + (w << 5) + rdseg * 8;
#pragma unroll
    for (int cc = 0; cc < 2; ++cc) {
      f32x4 v;
#pragma unroll
      for (int e = 0; e < 4; ++e)
        v[e] = scrf[(rdseg * 8 + cc * 4 + e) * 16 + rdrow];
      *(f32x4*)&p[cc * 4] = v;
    }
  }
}

// ---------------------------------------------------------------------------
// softmax fragment build (T12): s holds S^T regs for one 32-key block
// (key = (r&3) + 8*(r>>2) + 4*hl, q = ln31). exp2 in place, then
// cvt_pk pairs + permlane32_swap reassemble the PV A-fragments entirely
// in registers — no P LDS round-trip.
// ---------------------------------------------------------------------------
__device__ __forceinline__ void softmax_frag(const f32x16& s, float& l,
                                             bf16x8& pfa, bf16x8& pfb)
{
  float p[16];
#pragma unroll
  for (int r = 0; r < 16; ++r) {
    p[r] = __builtin_amdgcn_exp2f(s[r]);
    l += p[r];
  }
  unsigned A0 = cvtpk_bf16(p[0],  p[1]);   // (0,1)   | (4,5)
  unsigned A1 = cvtpk_bf16(p[2],  p[3]);   // (2,3)   | (6,7)
  unsigned B0 = cvtpk_bf16(p[4],  p[5]);   // (8,9)   | (12,13)
  unsigned B1 = cvtpk_bf16(p[6],  p[7]);   // (10,11) | (14,15)
  unsigned C0 = cvtpk_bf16(p[8],  p[9]);   // (16,17) | (20,21)
  unsigned C1 = cvtpk_bf16(p[10], p[11]);  // (18,19) | (22,23)
  unsigned D0 = cvtpk_bf16(p[12], p[13]);  // (24,25) | (28,29)
  unsigned D1 = cvtpk_bf16(p[14], p[15]);  // (26,27) | (30,31)
  plswap(A0, B0);
  plswap(A1, B1);
  plswap(C0, D0);
  plswap(C1, D1);
  union { unsigned u[4]; bf16x8 v; } ua, ub;
  ua.u[0] = A0; ua.u[1] = A1; ua.u[2] = B0; ua.u[3] = B1;  // k 0..7 | 8..15
  ub.u[0] = C0; ub.u[1] = C1; ub.u[2] = D0; ub.u[3] = D1;  // k 16..23 | 24..31
  pfa = ua.v;
  pfb = ub.v;
}

// ---------------------------------------------------------------------------
// PV step: A-frag PF covers keys kh*64 + KS*16 + hl*8 .. +8
// ---------------------------------------------------------------------------
__device__ __forceinline__ void pvstep(const __bf16* Vs, int kh, int KS, int hl,
                                       int ln31, const bf16x8& PF,
                                       f32x16& o0, f32x16& o1)
{
  const int vchunk = (kh << 3) + 2 * KS + hl;
  bf16x8 vf0 = *(const bf16x8*)&Vs[ln31 * 128 + ((vchunk ^ (ln31 & 15)) << 3)];
  bf16x8 vf1 = *(const bf16x8*)&Vs[(32 + ln31) * 128 +
                                   ((vchunk ^ ((32 + ln31) & 15)) << 3)];
  o0 = __builtin_amdgcn_mfma_f32_32x32x16_bf16(PF, vf0, o0, 0, 0, 0);
  o1 = __builtin_amdgcn_mfma_f32_32x32x16_bf16(PF, vf1, o1, 0, 0, 0);
}

// per-128-key-tile compute for one wave (its 64-key half, two 32-key blocks)
__device__ __forceinline__ void attn_tile_compute(
    const __bf16* Ks, const __bf16* Vs, const bf16x8 (&qf)[4],
    int kh, int ln31, int hl, float& l_lane, f32x16& o0, f32x16& o1)
{
#pragma unroll
  for (int half = 0; half < 2; ++half) {
    f32x16 s;
#pragma unroll
    for (int r = 0; r < 16; ++r) s[r] = 0.f;
    const int kr = (kh << 6) + half * 32 + ln31;
    __builtin_amdgcn_s_setprio(1);
#pragma unroll
    for (int ks = 0; ks < 4; ++ks) {
      bf16x8 kf = *(const bf16x8*)&Ks[kr * 64 + (((2 * ks + hl) ^ (kr & 7)) << 3)];
      s = __builtin_amdgcn_mfma_f32_32x32x16_bf16(kf, qf[ks], s, 0, 0, 0);
    }
    __builtin_amdgcn_s_setprio(0);
    bf16x8 pa, pb;
    softmax_frag(s, l_lane, pa, pb);
    __builtin_amdgcn_s_setprio(1);
    pvstep(Vs, kh, half * 2 + 0, hl, ln31, pa, o0, o1);
    pvstep(Vs, kh, half * 2 + 1, hl, ln31, pb, o0, o1);
    __builtin_amdgcn_s_setprio(0);
  }
}

// ---------------------------------------------------------------------------
// Flash attention v8 — v7 (key-split 8-wave, in-register P) + K/V DOUBLE
// BUFFER. Per 128-key tile: issue next tile's DMA, compute current, single
// drain-barrier — staging latency hides under QK/softmax/PV compute.
// LDS 80 KB: Q 16 | K0 16 | V0 16 | K1 16 | V1 16. Grid is the binding
// occupancy limit (512 blocks / 256 CU = 2 blocks/CU) so dbuf is free.
// Static unroll-by-2 — no dynamic buffer index (r7 lesson).
// ---------------------------------------------------------------------------
__global__ __launch_bounds__(512, 4) void attn_kernel(
    const __bf16* __restrict__ Qb, const __bf16* __restrict__ Kb,
    const __bf16* __restrict__ Vtb, __bf16* __restrict__ Ob)
{
  __shared__ __align__(16) __bf16 smem[5 * 128 * 64];   // 80 KB
  __bf16* QP = smem;            // Q tile [q128][dk64]
  __bf16* K0 = smem + 8192;
  __bf16* V0 = smem + 16384;
  __bf16* K1 = smem + 24576;
  __bf16* V1 = smem + 32768;

  const int t = threadIdx.x, w = t >> 6, lane = t & 63;
  const int ln31 = lane & 31, hl = lane >> 5;
  const int g  = w & 3;         // q-group (32 rows of the 128-q tile)
  const int kh = w >> 2;        // key-half (64 keys) of the staged tile
  const int bh = blockIdx.x;    // b*NHEAD + h  (XCD-locality key)
  const int q0 = blockIdx.y * 128;
  const int bb = bh >> 4, hh = bh & 15;

  const __bf16* Qg = Qb + (size_t)bh * SEQ * DKH + (size_t)q0 * DKH;
  const __bf16* Kg = Kb + (size_t)bh * SEQ * DKH;
  const __bf16* Vg = Vtb + (size_t)bh * DKH * SEQ;

  // K/V tile stage: 1024 chunks K + 1024 chunks V over 512 threads = 2 issues
  auto stage_kv = [&](int kt, __bf16* Ks, __bf16* Vs) {
#pragma unroll
    for (int issue = 0; issue < 2; ++issue) {
      const int cbase = issue * 512 + (w << 6);
      const int c = cbase + lane;
      const int krow = c >> 3;                        // K: 8 chunks/row
      const int kgoff = ((c & 7) ^ (krow & 7)) << 3;
      async16(Kg + (size_t)(kt + krow) * DKH + kgoff, Ks + cbase * 8);
      const int vrow = c >> 4;                        // V: 16 chunks/row
      const int vgoff = ((c & 15) ^ (vrow & 15)) << 3;
      async16(Vg + (size_t)vrow * SEQ + kt + vgoff, Vs + cbase * 8);
    }
  };

  // prologue: stage Q tile + K/V tile 0
#pragma unroll
  for (int issue = 0; issue < 2; ++issue) {
    const int cbase = issue * 512 + (w << 6);
    const int c = cbase + lane;
    const int row = c >> 3;                         // 8 chunks per 64-elem row
    const int goff = ((c & 7) ^ (row & 7)) << 3;
    async16(Qg + (size_t)row * DKH + goff, QP + cbase * 8);
  }
  stage_kv(0, K0, V0);
  __syncthreads();

  // Q B-fragments for this wave's 32 q-rows (held in regs for whole kernel)
  const int qrow = (g << 5) + ln31;
  bf16x8 qf[4];
#pragma unroll
  for (int ks = 0; ks < 4; ++ks) {
    const int chunk = ((2 * ks + hl) ^ (qrow & 7));
    qf[ks] = *(const bf16x8*)&QP[qrow * 64 + (chunk << 3)];
  }

  float l_lane = 0.f;          // partial row-sum for q-row `qrow` (this key-half)
  f32x16 o0, o1;               // partial O[32q][64d]: d-blocks 0/1; d = db*32+ln31
#pragma unroll
  for (int r = 0; r < 16; ++r) { o0[r] = 0.f; o1[r] = 0.f; }

  for (int kt = 0; kt < SEQ; kt += 256) {     // two 128-key tiles per iter
    stage_kv(kt + 128, K1, V1);               // prefetch into idle buffer
    attn_tile_compute(K0, V0, qf, kh, ln31, hl, l_lane, o0, o1);
    __syncthreads();                          // drain tile t+1; buf0 reads done
    if (kt + 256 < SEQ)
      stage_kv(kt + 256, K0, V0);
    attn_tile_compute(K1, V1, qf, kh, ln31, hl, l_lane, o0, o1);
    __syncthreads();                          // drain tile t+2; buf1 reads done
  }

  // ---- cross-wave combine: pair (w, w+4) holds same q-rows, disjoint keys.
  // Waves 4..7 dump partial O (8 KB each) + l into dead Q/K LDS; waves
  // 0..3 sum, normalize, store. (Loop's final barrier already synced.)
  float* cmb = (float*)smem;             // pair region: [d64][q32] f32
  const int dsw = ln31 & 7;
  l_lane += __shfl_xor(l_lane, 32);      // both key-sub-blocks of this wave

  if (w >= 4) {
    float* base = cmb + (g << 11);
#pragma unroll
    for (int gg = 0; gg < 4; ++gg) {
      const int qq = ((2 * gg + hl) ^ dsw) << 2;   // swizzled q-quad slot
      f32x4 va, vb;
#pragma unroll
      for (int rr = 0; rr < 4; ++rr) { va[rr] = o0[4 * gg + rr]; vb[rr] = o1[4 * gg + rr]; }
      *(f32x4*)&base[ln31 * 32 + qq]        = va;   // d = ln31
      *(f32x4*)&base[(32 + ln31) * 32 + qq] = vb;   // d = 32+ln31
    }
    if (hl == 0) cmb[8192 + (g << 5) + ln31] = l_lane;   // l region
  }
  __syncthreads();
  if (w < 4) {
    float* base = cmb + (g << 11);
#pragma unroll
    for (int gg = 0; gg < 4; ++gg) {
      const int qq = ((2 * gg + hl) ^ dsw) << 2;
      const f32x4 va = *(const f32x4*)&base[ln31 * 32 + qq];
      const f32x4 vb = *(const f32x4*)&base[(32 + ln31) * 32 + qq];
#pragma unroll
      for (int rr = 0; rr < 4; ++rr) { o0[4 * gg + rr] += va[rr]; o1[4 * gg + rr] += vb[rr]; }
    }
    const float inv = 1.0f / (l_lane + cmb[8192 + (g << 5) + ln31]);

    // epilogue: O[b, q, h*64+d]; lane = d col; fetch inv via shfl
#pragma unroll
    for (int r = 0; r < 16; ++r) {
      const int qi = (r & 3) + 8 * (r >> 2) + 4 * hl;    // q within wave's 32
      const float iq = __shfl(inv, qi);                  // from lane qi (hl=0 half)
      const int q = q0 + (g << 5) + qi;
      __bf16* rowp = Ob + ((size_t)(bb * SEQ + q)) * DMODEL + hh * DKH;
      rowp[ln31]      = (__bf16)(o0[r] * iq);
      rowp[32 + ln31] = (__bf16)(o1[r] * iq);
    }
  }
}

// ---------------------------------------------------------------------------
extern "C" void kernel_launch(void* const* d_in, const int* in_sizes, int n_in,
                              void* d_out, int out_size, void* d_ws, size_t ws_size,
                              hipStream_t stream)
{
  const float* x  = (const float*)d_in[0];
  const float* Wq = (const float*)d_in[1];
  const float* bq = (const float*)d_in[2];
  const float* Wk = (const float*)d_in[3];
  const float* bk = (const float*)d_in[4];
  const float* Wv = (const float*)d_in[5];
  const float* bv = (const float*)d_in[6];
  const float* Wo = (const float*)d_in[7];
  const float* bo = (const float*)d_in[8];
  float*  out = (float*)d_out;
  __bf16* ws  = (__bf16*)d_ws;

  // fp32 -> bf16 for x and the 4 weight matrices (one launch)
  cvt_fp32_bf16<<<dim3(2048, 5, 1), 256, 0, stream>>>(x, Wq, Wk, Wv, Wo, ws);

  // Q,K,V projections (fused, grid.z picks the matrix)
  qkv_gemm<<<dim3(MTOT / 128, DMODEL / 128, 3), 256, 0, stream>>>(
      ws + XB, ws + WQB, bq, ws + WKB, bk, ws + WVB, bv, ws);

  // flash attention: (bh, q-tile of 128) = 512 blocks x 512 threads
  attn_kernel<<<dim3(BATCH * NHEAD, SEQ / 128), 512, 0, stream>>>(
      ws + QOFF, ws + KOFF, ws + VOFF, ws + OOFF);

  // output projection -> fp32 d_out (64x128 tiles, 512 blocks)
  out_gemm<<<dim3(MTOT / 64, DMODEL / 128), 256, 0, stream>>>(
      ws + OOFF, ws + WOB, bo, out);
}

// Round 3
// 190.256 us; speedup vs baseline: 1.0127x; 1.0127x over previous
//
#include <hip/hip_runtime.h>

// ---------- problem constants ----------
#define BATCH   2
#define SEQ     2048
#define DMODEL  1024
#define NHEAD   16
#define DKH     64
#define MTOT    (BATCH*SEQ)      // 4096 rows for the projection GEMMs
#define KDIM    DMODEL           // 1024 contraction for projections

// ws layout in bf16 elements (total 24M bf16 = 48 MB)
#define XB    0u                     // x bf16            [4096,1024]  4M
#define WQB   (4u*1024u*1024u)       // Wq bf16           [1024,1024]  1M
#define WKB   (5u*1024u*1024u)
#define WVB   (6u*1024u*1024u)
#define WOB   (7u*1024u*1024u)
#define QOFF  (8u*1024u*1024u)       // Q  [B,H,N,dk] (pre-scaled log2e/8) 4M
#define KOFF  (12u*1024u*1024u)      // K  [B,H,N,dk]                  4M
#define VOFF  (16u*1024u*1024u)      // V^T [B,H,dk,N]                 4M
#define OOFF  (20u*1024u*1024u)      // attn out, flat [B,N,D]         4M

typedef __bf16 bf16x8 __attribute__((ext_vector_type(8)));
typedef __bf16 bf16x4 __attribute__((ext_vector_type(4)));
typedef float  f32x4  __attribute__((ext_vector_type(4)));
typedef float  f32x16 __attribute__((ext_vector_type(16)));

// async global->LDS, 16B per lane; LDS dest is wave-uniform base (HW adds lane*16)
__device__ __forceinline__ void async16(const __bf16* g, __bf16* l) {
  __builtin_amdgcn_global_load_lds(
      (const __attribute__((address_space(1))) void*)g,
      (__attribute__((address_space(3))) void*)l, 16, 0, 0);
}

// packed f32x2 -> bf16x2 (dword): lo in low 16 bits (T12 recipe, no builtin)
__device__ __forceinline__ unsigned cvtpk_bf16(float lo, float hi) {
  unsigned r;
  asm("v_cvt_pk_bf16_f32 %0, %1, %2" : "=v"(r) : "v"(lo), "v"(hi));
  return r;
}
// v_permlane32_swap_b32: a.hi32lanes <-> b.lo32lanes
__device__ __forceinline__ void plswap(unsigned& a, unsigned& b) {
  asm("v_permlane32_swap_b32 %0, %1" : "+v"(a), "+v"(b));
}

// ---------------------------------------------------------------------------
// fp32 -> bf16 conversion: blockIdx.y selects tensor (0:x, 1..4:Wq/Wk/Wv/Wo)
// ---------------------------------------------------------------------------
__global__ __launch_bounds__(256) void cvt_fp32_bf16(
    const float* __restrict__ x,  const float* __restrict__ wq,
    const float* __restrict__ wk, const float* __restrict__ wv,
    const float* __restrict__ wo, __bf16* __restrict__ ws)
{
  const float* src; __bf16* dst; int n;
  switch (blockIdx.y) {
    case 0:  src = x;  dst = ws + XB;  n = 4 * 1024 * 1024; break;
    case 1:  src = wq; dst = ws + WQB; n = 1024 * 1024;     break;
    case 2:  src = wk; dst = ws + WKB; n = 1024 * 1024;     break;
    case 3:  src = wv; dst = ws + WVB; n = 1024 * 1024;     break;
    default: src = wo; dst = ws + WOB; n = 1024 * 1024;     break;
  }
  const int i = (blockIdx.x * 256 + threadIdx.x) * 8;
  if (i < n) {
    const float4 a = *(const float4*)(src + i);
    const float4 b = *(const float4*)(src + i + 4);
    bf16x8 o;
    o[0] = (__bf16)a.x; o[1] = (__bf16)a.y; o[2] = (__bf16)a.z; o[3] = (__bf16)a.w;
    o[4] = (__bf16)b.x; o[5] = (__bf16)b.y; o[6] = (__bf16)b.z; o[7] = (__bf16)b.w;
    *(bf16x8*)(dst + i) = o;
  }
}

// ---------------------------------------------------------------------------
// 128x128 NT-GEMM core, BK=32 (single-buffer — R2 showed explicit dbuf is
// net-negative here: compiler's vmcnt(0)-before-barrier drains the prefetch
// anyway and the extra live state spilled).
// lds: A-tile [0,4096), B-tile [4096,8192) (16 KB).
// 16B-chunk XOR swizzle: chunk' = chunk ^ (row & 3).
// ---------------------------------------------------------------------------
__device__ __forceinline__ void gemm128_core(
    const __bf16* __restrict__ A, const __bf16* __restrict__ W,
    int m0, int n0, __bf16* lds, f32x4 (&acc)[4][4])
{
  __bf16* A_lds = lds;
  __bf16* B_lds = lds + 4096;
  const int t    = threadIdx.x;
  const int w    = t >> 6;
  const int lane = t & 63;
  const int ln15 = lane & 15;
  const int quad = lane >> 4;
  const int wr   = (w >> 1) << 6;   // wave row offset within 128
  const int wc   = (w & 1) << 6;    // wave col offset within 128

#pragma unroll
  for (int i = 0; i < 4; ++i)
#pragma unroll
    for (int j = 0; j < 4; ++j) acc[i][j] = (f32x4){0.f, 0.f, 0.f, 0.f};

  for (int kt = 0; kt < KDIM; kt += 32) {
    __syncthreads();   // previous tile's LDS reads done
#pragma unroll
    for (int issue = 0; issue < 2; ++issue) {
      const int cbase = issue * 256 + (w << 6);
      const int c     = cbase + lane;
      const int row   = c >> 2;                       // 4 chunks (32 bf16) per row
      const int goff  = ((c & 3) ^ (row & 3)) << 3;   // swizzled source chunk
      async16(A + (size_t)(m0 + row) * KDIM + kt + goff, A_lds + cbase * 8);
      async16(W + (size_t)(n0 + row) * KDIM + kt + goff, B_lds + cbase * 8);
    }
    __syncthreads();   // vmcnt(0) drain: LDS tiles valid

    bf16x8 af[4], bfr[4];
#pragma unroll
    for (int i = 0; i < 4; ++i) {
      const int row = wr + i * 16 + ln15;
      af[i] = *(const bf16x8*)&A_lds[row * 32 + ((quad ^ (row & 3)) << 3)];
    }
#pragma unroll
    for (int j = 0; j < 4; ++j) {
      const int row = wc + j * 16 + ln15;
      bfr[j] = *(const bf16x8*)&B_lds[row * 32 + ((quad ^ (row & 3)) << 3)];
    }
#pragma unroll
    for (int i = 0; i < 4; ++i)
#pragma unroll
      for (int j = 0; j < 4; ++j)
        acc[i][j] = __builtin_amdgcn_mfma_f32_16x16x32_bf16(af[i], bfr[j], acc[i][j], 0, 0, 0);
  }
}

// ---------------------------------------------------------------------------
// Fused QKV projection: z=0 -> Q (scaled log2e/8) [B,H,N,dk]; z=1 -> K;
// z=2 -> V transposed [B,H,dk,N]. Biases fp32. 16B vectorized stores via
// per-wave LDS repack.
// ---------------------------------------------------------------------------
__global__ __launch_bounds__(256) void qkv_gemm(
    const __bf16* __restrict__ X,
    const __bf16* __restrict__ Wq, const float* __restrict__ bq,
    const __bf16* __restrict__ Wk, const float* __restrict__ bk,
    const __bf16* __restrict__ Wv, const float* __restrict__ bv,
    __bf16* __restrict__ ws)
{
  __shared__ __align__(16) __bf16 lds[128 * 64];   // 16 KB

  const int z = blockIdx.z;
  const __bf16* W    = (z == 0) ? Wq : (z == 1) ? Wk : Wv;
  const float*  bias = (z == 0) ? bq : (z == 1) ? bk : bv;
  __bf16* out = ws + ((z == 0) ? QOFF : (z == 1) ? KOFF : VOFF);
  // softmax runs in exp2 domain: fold 1/sqrt(dk) * log2(e) into Q
  const float scale = (z == 0) ? 0.125f * 1.44269504088896f : 1.0f;

  const int m0 = blockIdx.x * 128;
  const int n0 = blockIdx.y * 128;

  f32x4 acc[4][4];
  gemm128_core(X, W, m0, n0, lds, acc);

  const int t = threadIdx.x, w = t >> 6, lane = t & 63;
  const int ln15 = lane & 15, quad = lane >> 4;
  const int wr = (w >> 1) << 6, wc = (w & 1) << 6;

  // bias values for this wave's 64 columns (col = j*16+ln15)
  float bj4[4];
#pragma unroll
  for (int j = 0; j < 4; ++j) bj4[j] = bias[n0 + wc + j * 16 + ln15];

  __syncthreads();                     // all waves done reading K-tiles
  __bf16* scr = lds + (w << 10);       // per-wave 1024-elem scratch (2 KB)

  const int bb = m0 >> 11;             // batch (blocks never straddle)
  const int s_base = (m0 & 2047) + wr;
  const int h = (n0 + wc) >> 6;

  if (z != 2) {
    // ---- Q/K [B,H,N,dk]: row-major scratch [row16][d64], coalesced stores
    const int rdrow = lane & 15, rdseg = lane >> 4;
#pragma unroll
    for (int i = 0; i < 4; ++i) {
#pragma unroll
      for (int j = 0; j < 4; ++j)
#pragma unroll
        for (int rr = 0; rr < 4; ++rr)
          scr[(quad * 4 + rr) * 64 + j * 16 + ln15] =
              (__bf16)((acc[i][j][rr] + bj4[j]) * scale);
      // wave-private scratch: compiler orders via lgkmcnt, no barrier
      bf16x8 v0 = *(const bf16x8*)&scr[rdrow * 64 + rdseg * 16];
      bf16x8 v1 = *(const bf16x8*)&scr[rdrow * 64 + rdseg * 16 + 8];
      const int s = s_base + i * 16 + rdrow;
      __bf16* p = out + (((size_t)(bb * NHEAD + h)) * SEQ + s) * DKH + rdseg * 16;
      *(bf16x8*)p = v0;
      *(bf16x8*)&p[8] = v1;
    }
  } else {
    // ---- V^T [B,H,dk,N]: col-major scratch [d64][row16] does the transpose;
    // each lane then stores 32B contiguous in s.
#pragma unroll
    for (int i = 0; i < 4; ++i) {
#pragma unroll
      for (int j = 0; j < 4; ++j) {
        bf16x4 pk;
#pragma unroll
        for (int rr = 0; rr < 4; ++rr) pk[rr] = (__bf16)(acc[i][j][rr] + bj4[j]);
        *(bf16x4*)&scr[(j * 16 + ln15) * 16 + quad * 4] = pk;
      }
      bf16x8 c0 = *(const bf16x8*)&scr[lane * 16];
      bf16x8 c1 = *(const bf16x8*)&scr[lane * 16 + 8];
      __bf16* p = out + (((size_t)(bb * NHEAD + h)) * DKH + lane) * SEQ
                      + s_base + i * 16;
      *(bf16x8*)p = c0;
      *(bf16x8*)&p[8] = c1;
    }
  }
}

// ---------------------------------------------------------------------------
// Output projection: d_out(fp32) = O[M,K]bf16 @ Wo[N,K]bf16^T + bo(fp32).
// 64x128 tile -> 512 blocks (2/CU). 4 waves, each 64 rows x 32 cols.
// ---------------------------------------------------------------------------
__global__ __launch_bounds__(256) void out_gemm(
    const __bf16* __restrict__ A, const __bf16* __restrict__ Wo,
    const float* __restrict__ bo, float* __restrict__ out)
{
  __shared__ __align__(16) __bf16 lds[6144];   // A 64x32 | B 128x32 (12 KB)
  __bf16* A_lds = lds;
  __bf16* B_lds = lds + 2048;

  const int m0 = blockIdx.x * 64;
  const int n0 = blockIdx.y * 128;

  const int t = threadIdx.x, w = t >> 6, lane = t & 63;
  const int ln15 = lane & 15, quad = lane >> 4;

  f32x4 acc[4][2];
#pragma unroll
  for (int i = 0; i < 4; ++i)
#pragma unroll
    for (int j = 0; j < 2; ++j) acc[i][j] = (f32x4){0.f, 0.f, 0.f, 0.f};

  for (int kt = 0; kt < KDIM; kt += 32) {
    __syncthreads();
    {  // A: 64 rows x 4 chunks = 256 chunks = 1 issue
      const int c = (w << 6) + lane;
      const int row = c >> 2;
      const int goff = ((c & 3) ^ (row & 3)) << 3;
      async16(A + (size_t)(m0 + row) * KDIM + kt + goff, A_lds + c * 8);
    }
#pragma unroll
    for (int issue = 0; issue < 2; ++issue) {  // B: 128 rows x 4 chunks = 2 issues
      const int cbase = issue * 256 + (w << 6);
      const int c = cbase + lane;
      const int row = c >> 2;
      const int goff = ((c & 3) ^ (row & 3)) << 3;
      async16(Wo + (size_t)(n0 + row) * KDIM + kt + goff, B_lds + cbase * 8);
    }
    __syncthreads();

    bf16x8 af[4], bfr[2];
#pragma unroll
    for (int i = 0; i < 4; ++i) {
      const int row = i * 16 + ln15;
      af[i] = *(const bf16x8*)&A_lds[row * 32 + ((quad ^ (row & 3)) << 3)];
    }
#pragma unroll
    for (int j = 0; j < 2; ++j) {
      const int row = (w << 5) + j * 16 + ln15;
      bfr[j] = *(const bf16x8*)&B_lds[row * 32 + ((quad ^ (row & 3)) << 3)];
    }
#pragma unroll
    for (int i = 0; i < 4; ++i)
#pragma unroll
      for (int j = 0; j < 2; ++j)
        acc[i][j] = __builtin_amdgcn_mfma_f32_16x16x32_bf16(af[i], bfr[j], acc[i][j], 0, 0, 0);
  }

  float bj2[2];
#pragma unroll
  for (int j = 0; j < 2; ++j) bj2[j] = bo[n0 + (w << 5) + j * 16 + ln15];

  __syncthreads();                          // waves done reading A/B tiles
  float* scrf = (float*)lds + (w << 9);     // per-wave 512-float scratch (2 KB)

  const int rdrow = lane & 15, rdseg = lane >> 4;
#pragma unroll
  for (int i = 0; i < 4; ++i) {
#pragma unroll
    for (int j = 0; j < 2; ++j) {
      f32x4 v;
#pragma unroll
      for (int rr = 0; rr < 4; ++rr) v[rr] = acc[i][j][rr] + bj2[j];
      *(f32x4*)&scrf[(j * 16 + ln15) * 16 + quad * 4] = v;   // col-major
    }
    const int m = m0 + i * 16 + rdrow;
    float* p = out + (size_t)m * DMODEL + n0 + (w << 5) + rdseg * 8;
#pragma unroll
    for (int cc = 0; cc < 2; ++cc) {
      f32x4 v;
#pragma unroll
      for (int e = 0; e < 4; ++e)
        v[e] = scrf[(rdseg * 8 + cc * 4 + e) * 16 + rdrow];
      *(f32x4*)&p[cc * 4] = v;
    }
  }
}

// ---------------------------------------------------------------------------
// softmax fragment build (T12): s holds S^T regs for one 32-key block
// (key = (r&3) + 8*(r>>2) + 4*hl, q = ln31). exp2 in place, then
// cvt_pk pairs + permlane32_swap reassemble the PV A-fragments entirely
// in registers — no P LDS round-trip.
// ---------------------------------------------------------------------------
__device__ __forceinline__ void softmax_frag(const f32x16& s, float& l,
                                             bf16x8& pfa, bf16x8& pfb)
{
  float p[16];
#pragma unroll
  for (int r = 0; r < 16; ++r) {
    p[r] = __builtin_amdgcn_exp2f(s[r]);
    l += p[r];
  }
  unsigned A0 = cvtpk_bf16(p[0],  p[1]);   // (0,1)   | (4,5)
  unsigned A1 = cvtpk_bf16(p[2],  p[3]);   // (2,3)   | (6,7)
  unsigned B0 = cvtpk_bf16(p[4],  p[5]);   // (8,9)   | (12,13)
  unsigned B1 = cvtpk_bf16(p[6],  p[7]);   // (10,11) | (14,15)
  unsigned C0 = cvtpk_bf16(p[8],  p[9]);   // (16,17) | (20,21)
  unsigned C1 = cvtpk_bf16(p[10], p[11]);  // (18,19) | (22,23)
  unsigned D0 = cvtpk_bf16(p[12], p[13]);  // (24,25) | (28,29)
  unsigned D1 = cvtpk_bf16(p[14], p[15]);  // (26,27) | (30,31)
  plswap(A0, B0);
  plswap(A1, B1);
  plswap(C0, D0);
  plswap(C1, D1);
  union { unsigned u[4]; bf16x8 v; } ua, ub;
  ua.u[0] = A0; ua.u[1] = A1; ua.u[2] = B0; ua.u[3] = B1;  // k 0..7 | 8..15
  ub.u[0] = C0; ub.u[1] = C1; ub.u[2] = D0; ub.u[3] = D1;  // k 16..23 | 24..31
  pfa = ua.v;
  pfb = ub.v;
}

// ---------------------------------------------------------------------------
// PV step: A-frag PF covers keys kh*64 + KS*16 + hl*8 .. +8
// ---------------------------------------------------------------------------
__device__ __forceinline__ void pvstep(const __bf16* Vs, int kh, int KS, int hl,
                                       int ln31, const bf16x8& PF,
                                       f32x16& o0, f32x16& o1)
{
  const int vchunk = (kh << 3) + 2 * KS + hl;
  bf16x8 vf0 = *(const bf16x8*)&Vs[ln31 * 128 + ((vchunk ^ (ln31 & 15)) << 3)];
  bf16x8 vf1 = *(const bf16x8*)&Vs[(32 + ln31) * 128 +
                                   ((vchunk ^ ((32 + ln31) & 15)) << 3)];
  o0 = __builtin_amdgcn_mfma_f32_32x32x16_bf16(PF, vf0, o0, 0, 0, 0);
  o1 = __builtin_amdgcn_mfma_f32_32x32x16_bf16(PF, vf1, o1, 0, 0, 0);
}

// ---------------------------------------------------------------------------
// per-128-key-tile compute, T15-lite pipelined order:
//   QK0 ∥ QK1 (two independent MFMA accumulate chains, interleaved)
//   SM0 (VALU, overlaps QK tail) ; PV0 (MFMA) ; SM1 (VALU, overlaps PV0) ; PV1
// The old order QK0,SM0,PV0,QK1,SM1,PV1 was fully dependency-serialized —
// MFMA and VALU pipes never overlapped within a wave, and barrier-lockstep
// prevents cross-wave overlap. Cost: one extra f32x16 live (+16 VGPR).
// ---------------------------------------------------------------------------
__device__ __forceinline__ void attn_tile_compute(
    const __bf16* Ks, const __bf16* Vs, const bf16x8 (&qf)[4],
    int kh, int ln31, int hl, float& l_lane, f32x16& o0, f32x16& o1)
{
  f32x16 s0, s1;
#pragma unroll
  for (int r = 0; r < 16; ++r) { s0[r] = 0.f; s1[r] = 0.f; }
  const int kr0 = (kh << 6) + ln31;        // key row, half 0
  const int kr1 = (kh << 6) + 32 + ln31;   // key row, half 1

  __builtin_amdgcn_s_setprio(1);
#pragma unroll
  for (int ks = 0; ks < 4; ++ks) {
    bf16x8 kf0 = *(const bf16x8*)&Ks[kr0 * 64 + (((2 * ks + hl) ^ (kr0 & 7)) << 3)];
    bf16x8 kf1 = *(const bf16x8*)&Ks[kr1 * 64 + (((2 * ks + hl) ^ (kr1 & 7)) << 3)];
    s0 = __builtin_amdgcn_mfma_f32_32x32x16_bf16(kf0, qf[ks], s0, 0, 0, 0);
    s1 = __builtin_amdgcn_mfma_f32_32x32x16_bf16(kf1, qf[ks], s1, 0, 0, 0);
  }
  __builtin_amdgcn_s_setprio(0);

  bf16x8 pa0, pb0;
  softmax_frag(s0, l_lane, pa0, pb0);      // overlaps QK1 MFMA drain
  __builtin_amdgcn_s_setprio(1);
  pvstep(Vs, kh, 0, hl, ln31, pa0, o0, o1);
  pvstep(Vs, kh, 1, hl, ln31, pb0, o0, o1);
  __builtin_amdgcn_s_setprio(0);

  bf16x8 pa1, pb1;
  softmax_frag(s1, l_lane, pa1, pb1);      // overlaps PV0 MFMAs
  __builtin_amdgcn_s_setprio(1);
  pvstep(Vs, kh, 2, hl, ln31, pa1, o0, o1);
  pvstep(Vs, kh, 3, hl, ln31, pb1, o0, o1);
  __builtin_amdgcn_s_setprio(0);
}

// ---------------------------------------------------------------------------
// Flash attention v9 — v7 structure (single-buffer 48 KB, verified 44.4 µs)
// + T15-lite in-tile pipeline (attn_tile_compute above). R2's K/V dbuf is
// REVERTED: it added scratch/L2 traffic (+12 MB writes) and regressed −10%.
// ---------------------------------------------------------------------------
__global__ __launch_bounds__(512, 4) void attn_kernel(
    const __bf16* __restrict__ Qb, const __bf16* __restrict__ Kb,
    const __bf16* __restrict__ Vtb, __bf16* __restrict__ Ob)
{
  __shared__ __align__(16) __bf16 smem[3 * 128 * 64];   // 48 KB
  __bf16* QP = smem;            // Q tile [q128][dk64]
  __bf16* Ks = smem + 8192;     // K tile [key128][dk64]
  __bf16* Vs = smem + 16384;    // V tile [d64][key128]

  const int t = threadIdx.x, w = t >> 6, lane = t & 63;
  const int ln31 = lane & 31, hl = lane >> 5;
  const int g  = w & 3;         // q-group (32 rows of the 128-q tile)
  const int kh = w >> 2;        // key-half (64 keys) of the staged tile
  const int bh = blockIdx.x;    // b*NHEAD + h  (XCD-locality key)
  const int q0 = blockIdx.y * 128;
  const int bb = bh >> 4, hh = bh & 15;

  const __bf16* Qg = Qb + (size_t)bh * SEQ * DKH + (size_t)q0 * DKH;
  const __bf16* Kg = Kb + (size_t)bh * SEQ * DKH;
  const __bf16* Vg = Vtb + (size_t)bh * DKH * SEQ;

  // stage Q tile (128x64 = 1024 chunks / 512 threads = 2 issues)
#pragma unroll
  for (int issue = 0; issue < 2; ++issue) {
    const int cbase = issue * 512 + (w << 6);
    const int c = cbase + lane;
    const int row = c >> 3;                         // 8 chunks per 64-elem row
    const int goff = ((c & 7) ^ (row & 7)) << 3;
    async16(Qg + (size_t)row * DKH + goff, QP + cbase * 8);
  }
  __syncthreads();

  // Q B-fragments for this wave's 32 q-rows (held in regs for whole kernel)
  const int qrow = (g << 5) + ln31;
  bf16x8 qf[4];
#pragma unroll
  for (int ks = 0; ks < 4; ++ks) {
    const int chunk = ((2 * ks + hl) ^ (qrow & 7));
    qf[ks] = *(const bf16x8*)&QP[qrow * 64 + (chunk << 3)];
  }

  float l_lane = 0.f;          // partial row-sum for q-row `qrow` (this key-half)
  f32x16 o0, o1;               // partial O[32q][64d]: d-blocks 0/1; d = db*32+ln31
#pragma unroll
  for (int r = 0; r < 16; ++r) { o0[r] = 0.f; o1[r] = 0.f; }

  for (int kt = 0; kt < SEQ; kt += 128) {
    __syncthreads();   // prior tile's Ks/Vs reads done; iter 0: Q reads done
#pragma unroll
    for (int issue = 0; issue < 2; ++issue) {
      const int cbase = issue * 512 + (w << 6);
      const int c = cbase + lane;
      // K [128 keys][64 dk]: 8 chunks/row
      const int krow = c >> 3;
      const int kgoff = ((c & 7) ^ (krow & 7)) << 3;
      async16(Kg + (size_t)(kt + krow) * DKH + kgoff, Ks + cbase * 8);
      // V [64 d][128 keys]: 16 chunks/row
      const int vrow = c >> 4;
      const int vgoff = ((c & 15) ^ (vrow & 15)) << 3;
      async16(Vg + (size_t)vrow * SEQ + kt + vgoff, Vs + cbase * 8);
    }
    __syncthreads();   // staging drain: Ks/Vs valid

    attn_tile_compute(Ks, Vs, qf, kh, ln31, hl, l_lane, o0, o1);
  }

  // ---- cross-wave combine: pair (w, w+4) holds same q-rows, disjoint keys.
  // Waves 4..7 dump partial O (8 KB each) + l into dead Q/K LDS; waves
  // 0..3 sum, normalize, store.
  __syncthreads();                       // all Ks/Vs LDS reads done
  float* cmb = (float*)smem;             // pair region: [d64][q32] f32
  const int dsw = ln31 & 7;
  l_lane += __shfl_xor(l_lane, 32);      // both key-sub-blocks of this wave

  if (w >= 4) {
    float* base = cmb + (g << 11);
#pragma unroll
    for (int gg = 0; gg < 4; ++gg) {
      const int qq = ((2 * gg + hl) ^ dsw) << 2;   // swizzled q-quad slot
      f32x4 va, vb;
#pragma unroll
      for (int rr = 0; rr < 4; ++rr) { va[rr] = o0[4 * gg + rr]; vb[rr] = o1[4 * gg + rr]; }
      *(f32x4*)&base[ln31 * 32 + qq]        = va;   // d = ln31
      *(f32x4*)&base[(32 + ln31) * 32 + qq] = vb;   // d = 32+ln31
    }
    if (hl == 0) cmb[8192 + (g << 5) + ln31] = l_lane;   // l region
  }
  __syncthreads();
  if (w < 4) {
    float* base = cmb + (g << 11);
#pragma unroll
    for (int gg = 0; gg < 4; ++gg) {
      const int qq = ((2 * gg + hl) ^ dsw) << 2;
      const f32x4 va = *(const f32x4*)&base[ln31 * 32 + qq];
      const f32x4 vb = *(const f32x4*)&base[(32 + ln31) * 32 + qq];
#pragma unroll
      for (int rr = 0; rr < 4; ++rr) { o0[4 * gg + rr] += va[rr]; o1[4 * gg + rr] += vb[rr]; }
    }
    const float inv = 1.0f / (l_lane + cmb[8192 + (g << 5) + ln31]);

    // epilogue: O[b, q, h*64+d]; lane = d col; fetch inv via shfl
#pragma unroll
    for (int r = 0; r < 16; ++r) {
      const int qi = (r & 3) + 8 * (r >> 2) + 4 * hl;    // q within wave's 32
      const float iq = __shfl(inv, qi);                  // from lane qi (hl=0 half)
      const int q = q0 + (g << 5) + qi;
      __bf16* rowp = Ob + ((size_t)(bb * SEQ + q)) * DMODEL + hh * DKH;
      rowp[ln31]      = (__bf16)(o0[r] * iq);
      rowp[32 + ln31] = (__bf16)(o1[r] * iq);
    }
  }
}

// ---------------------------------------------------------------------------
extern "C" void kernel_launch(void* const* d_in, const int* in_sizes, int n_in,
                              void* d_out, int out_size, void* d_ws, size_t ws_size,
                              hipStream_t stream)
{
  const float* x  = (const float*)d_in[0];
  const float* Wq = (const float*)d_in[1];
  const float* bq = (const float*)d_in[2];
  const float* Wk = (const float*)d_in[3];
  const float* bk = (const float*)d_in[4];
  const float* Wv = (const float*)d_in[5];
  const float* bv = (const float*)d_in[6];
  const float* Wo = (const float*)d_in[7];
  const float* bo = (const float*)d_in[8];
  float*  out = (float*)d_out;
  __bf16* ws  = (__bf16*)d_ws;

  // fp32 -> bf16 for x and the 4 weight matrices (one launch)
  cvt_fp32_bf16<<<dim3(2048, 5, 1), 256, 0, stream>>>(x, Wq, Wk, Wv, Wo, ws);

  // Q,K,V projections (fused, grid.z picks the matrix)
  qkv_gemm<<<dim3(MTOT / 128, DMODEL / 128, 3), 256, 0, stream>>>(
      ws + XB, ws + WQB, bq, ws + WKB, bk, ws + WVB, bv, ws);

  // flash attention: (bh, q-tile of 128) = 512 blocks x 512 threads
  attn_kernel<<<dim3(BATCH * NHEAD, SEQ / 128), 512, 0, stream>>>(
      ws + QOFF, ws + KOFF, ws + VOFF, ws + OOFF);

  // output projection -> fp32 d_out (64x128 tiles, 512 blocks)
  out_gemm<<<dim3(MTOT / 64, DMODEL / 128), 256, 0, stream>>>(
      ws + OOFF, ws + WOB, bo, out);
}

// Round 4
// 186.413 us; speedup vs baseline: 1.0336x; 1.0206x over previous
//
#include <hip/hip_runtime.h>

// ---------- problem constants ----------
#define BATCH   2
#define SEQ     2048
#define DMODEL  1024
#define NHEAD   16
#define DKH     64
#define MTOT    (BATCH*SEQ)      // 4096 rows for the projection GEMMs
#define KDIM    DMODEL           // 1024 contraction for projections

// ws layout in bf16 elements (total 24M bf16 = 48 MB)
#define XB    0u                     // x bf16            [4096,1024]  4M
#define WQB   (4u*1024u*1024u)       // Wq bf16           [1024,1024]  1M
#define WKB   (5u*1024u*1024u)
#define WVB   (6u*1024u*1024u)
#define WOB   (7u*1024u*1024u)
#define QOFF  (8u*1024u*1024u)       // Q  [B,H,N,dk] (pre-scaled log2e/8) 4M
#define KOFF  (12u*1024u*1024u)      // K  [B,H,N,dk]                  4M
#define VOFF  (16u*1024u*1024u)      // V^T [B,H,dk,N]                 4M
#define OOFF  (20u*1024u*1024u)      // attn out, flat [B,N,D]         4M

typedef __bf16 bf16x8 __attribute__((ext_vector_type(8)));
typedef __bf16 bf16x4 __attribute__((ext_vector_type(4)));
typedef float  f32x4  __attribute__((ext_vector_type(4)));
typedef float  f32x16 __attribute__((ext_vector_type(16)));

// async global->LDS, 16B per lane; LDS dest is wave-uniform base (HW adds lane*16)
__device__ __forceinline__ void async16(const __bf16* g, __bf16* l) {
  __builtin_amdgcn_global_load_lds(
      (const __attribute__((address_space(1))) void*)g,
      (__attribute__((address_space(3))) void*)l, 16, 0, 0);
}

// packed f32x2 -> bf16x2 (dword): lo in low 16 bits (T12 recipe, no builtin)
__device__ __forceinline__ unsigned cvtpk_bf16(float lo, float hi) {
  unsigned r;
  asm("v_cvt_pk_bf16_f32 %0, %1, %2" : "=v"(r) : "v"(lo), "v"(hi));
  return r;
}
// v_permlane32_swap_b32: a.hi32lanes <-> b.lo32lanes
__device__ __forceinline__ void plswap(unsigned& a, unsigned& b) {
  asm("v_permlane32_swap_b32 %0, %1" : "+v"(a), "+v"(b));
}

// ---------------------------------------------------------------------------
// fp32 -> bf16 conversion: blockIdx.y selects tensor (0:x, 1..4:Wq/Wk/Wv/Wo)
// ---------------------------------------------------------------------------
__global__ __launch_bounds__(256) void cvt_fp32_bf16(
    const float* __restrict__ x,  const float* __restrict__ wq,
    const float* __restrict__ wk, const float* __restrict__ wv,
    const float* __restrict__ wo, __bf16* __restrict__ ws)
{
  const float* src; __bf16* dst; int n;
  switch (blockIdx.y) {
    case 0:  src = x;  dst = ws + XB;  n = 4 * 1024 * 1024; break;
    case 1:  src = wq; dst = ws + WQB; n = 1024 * 1024;     break;
    case 2:  src = wk; dst = ws + WKB; n = 1024 * 1024;     break;
    case 3:  src = wv; dst = ws + WVB; n = 1024 * 1024;     break;
    default: src = wo; dst = ws + WOB; n = 1024 * 1024;     break;
  }
  const int i = (blockIdx.x * 256 + threadIdx.x) * 8;
  if (i < n) {
    const float4 a = *(const float4*)(src + i);
    const float4 b = *(const float4*)(src + i + 4);
    bf16x8 o;
    o[0] = (__bf16)a.x; o[1] = (__bf16)a.y; o[2] = (__bf16)a.z; o[3] = (__bf16)a.w;
    o[4] = (__bf16)b.x; o[5] = (__bf16)b.y; o[6] = (__bf16)b.z; o[7] = (__bf16)b.w;
    *(bf16x8*)(dst + i) = o;
  }
}

// ---------------------------------------------------------------------------
// 128x128 NT-GEMM core, BK=32 (single-buffer — R2 showed explicit dbuf is
// net-negative here). lds: A-tile [0,4096), B-tile [4096,8192) (16 KB).
// 16B-chunk XOR swizzle: chunk' = chunk ^ (row & 3).
// ---------------------------------------------------------------------------
__device__ __forceinline__ void gemm128_core(
    const __bf16* __restrict__ A, const __bf16* __restrict__ W,
    int m0, int n0, __bf16* lds, f32x4 (&acc)[4][4])
{
  __bf16* A_lds = lds;
  __bf16* B_lds = lds + 4096;
  const int t    = threadIdx.x;
  const int w    = t >> 6;
  const int lane = t & 63;
  const int ln15 = lane & 15;
  const int quad = lane >> 4;
  const int wr   = (w >> 1) << 6;   // wave row offset within 128
  const int wc   = (w & 1) << 6;    // wave col offset within 128

#pragma unroll
  for (int i = 0; i < 4; ++i)
#pragma unroll
    for (int j = 0; j < 4; ++j) acc[i][j] = (f32x4){0.f, 0.f, 0.f, 0.f};

  for (int kt = 0; kt < KDIM; kt += 32) {
    __syncthreads();   // previous tile's LDS reads done
#pragma unroll
    for (int issue = 0; issue < 2; ++issue) {
      const int cbase = issue * 256 + (w << 6);
      const int c     = cbase + lane;
      const int row   = c >> 2;                       // 4 chunks (32 bf16) per row
      const int goff  = ((c & 3) ^ (row & 3)) << 3;   // swizzled source chunk
      async16(A + (size_t)(m0 + row) * KDIM + kt + goff, A_lds + cbase * 8);
      async16(W + (size_t)(n0 + row) * KDIM + kt + goff, B_lds + cbase * 8);
    }
    __syncthreads();   // vmcnt(0) drain: LDS tiles valid

    bf16x8 af[4], bfr[4];
#pragma unroll
    for (int i = 0; i < 4; ++i) {
      const int row = wr + i * 16 + ln15;
      af[i] = *(const bf16x8*)&A_lds[row * 32 + ((quad ^ (row & 3)) << 3)];
    }
#pragma unroll
    for (int j = 0; j < 4; ++j) {
      const int row = wc + j * 16 + ln15;
      bfr[j] = *(const bf16x8*)&B_lds[row * 32 + ((quad ^ (row & 3)) << 3)];
    }
#pragma unroll
    for (int i = 0; i < 4; ++i)
#pragma unroll
      for (int j = 0; j < 4; ++j)
        acc[i][j] = __builtin_amdgcn_mfma_f32_16x16x32_bf16(af[i], bfr[j], acc[i][j], 0, 0, 0);
  }
}

// ---------------------------------------------------------------------------
// Fused QKV projection: z=0 -> Q (scaled log2e/8) [B,H,N,dk]; z=1 -> K;
// z=2 -> V transposed [B,H,dk,N]. Biases fp32. 16B vectorized stores via
// per-wave LDS repack.
// ---------------------------------------------------------------------------
__global__ __launch_bounds__(256) void qkv_gemm(
    const __bf16* __restrict__ X,
    const __bf16* __restrict__ Wq, const float* __restrict__ bq,
    const __bf16* __restrict__ Wk, const float* __restrict__ bk,
    const __bf16* __restrict__ Wv, const float* __restrict__ bv,
    __bf16* __restrict__ ws)
{
  __shared__ __align__(16) __bf16 lds[128 * 64];   // 16 KB

  const int z = blockIdx.z;
  const __bf16* W    = (z == 0) ? Wq : (z == 1) ? Wk : Wv;
  const float*  bias = (z == 0) ? bq : (z == 1) ? bk : bv;
  __bf16* out = ws + ((z == 0) ? QOFF : (z == 1) ? KOFF : VOFF);
  // softmax runs in exp2 domain: fold 1/sqrt(dk) * log2(e) into Q
  const float scale = (z == 0) ? 0.125f * 1.44269504088896f : 1.0f;

  const int m0 = blockIdx.x * 128;
  const int n0 = blockIdx.y * 128;

  f32x4 acc[4][4];
  gemm128_core(X, W, m0, n0, lds, acc);

  const int t = threadIdx.x, w = t >> 6, lane = t & 63;
  const int ln15 = lane & 15, quad = lane >> 4;
  const int wr = (w >> 1) << 6, wc = (w & 1) << 6;

  // bias values for this wave's 64 columns (col = j*16+ln15)
  float bj4[4];
#pragma unroll
  for (int j = 0; j < 4; ++j) bj4[j] = bias[n0 + wc + j * 16 + ln15];

  __syncthreads();                     // all waves done reading K-tiles
  __bf16* scr = lds + (w << 10);       // per-wave 1024-elem scratch (2 KB)

  const int bb = m0 >> 11;             // batch (blocks never straddle)
  const int s_base = (m0 & 2047) + wr;
  const int h = (n0 + wc) >> 6;

  if (z != 2) {
    // ---- Q/K [B,H,N,dk]: row-major scratch [row16][d64], coalesced stores
    const int rdrow = lane & 15, rdseg = lane >> 4;
#pragma unroll
    for (int i = 0; i < 4; ++i) {
#pragma unroll
      for (int j = 0; j < 4; ++j)
#pragma unroll
        for (int rr = 0; rr < 4; ++rr)
          scr[(quad * 4 + rr) * 64 + j * 16 + ln15] =
              (__bf16)((acc[i][j][rr] + bj4[j]) * scale);
      // wave-private scratch: compiler orders via lgkmcnt, no barrier
      bf16x8 v0 = *(const bf16x8*)&scr[rdrow * 64 + rdseg * 16];
      bf16x8 v1 = *(const bf16x8*)&scr[rdrow * 64 + rdseg * 16 + 8];
      const int s = s_base + i * 16 + rdrow;
      __bf16* p = out + (((size_t)(bb * NHEAD + h)) * SEQ + s) * DKH + rdseg * 16;
      *(bf16x8*)p = v0;
      *(bf16x8*)&p[8] = v1;
    }
  } else {
    // ---- V^T [B,H,dk,N]: col-major scratch [d64][row16] does the transpose;
    // each lane then stores 32B contiguous in s.
#pragma unroll
    for (int i = 0; i < 4; ++i) {
#pragma unroll
      for (int j = 0; j < 4; ++j) {
        bf16x4 pk;
#pragma unroll
        for (int rr = 0; rr < 4; ++rr) pk[rr] = (__bf16)(acc[i][j][rr] + bj4[j]);
        *(bf16x4*)&scr[(j * 16 + ln15) * 16 + quad * 4] = pk;
      }
      bf16x8 c0 = *(const bf16x8*)&scr[lane * 16];
      bf16x8 c1 = *(const bf16x8*)&scr[lane * 16 + 8];
      __bf16* p = out + (((size_t)(bb * NHEAD + h)) * DKH + lane) * SEQ
                      + s_base + i * 16;
      *(bf16x8*)p = c0;
      *(bf16x8*)&p[8] = c1;
    }
  }
}

// ---------------------------------------------------------------------------
// Output projection: d_out(fp32) = O[M,K]bf16 @ Wo[N,K]bf16^T + bo(fp32).
// 64x128 tile -> 512 blocks (2/CU). 4 waves, each 64 rows x 32 cols.
// ---------------------------------------------------------------------------
__global__ __launch_bounds__(256) void out_gemm(
    const __bf16* __restrict__ A, const __bf16* __restrict__ Wo,
    const float* __restrict__ bo, float* __restrict__ out)
{
  __shared__ __align__(16) __bf16 lds[6144];   // A 64x32 | B 128x32 (12 KB)
  __bf16* A_lds = lds;
  __bf16* B_lds = lds + 2048;

  const int m0 = blockIdx.x * 64;
  const int n0 = blockIdx.y * 128;

  const int t = threadIdx.x, w = t >> 6, lane = t & 63;
  const int ln15 = lane & 15, quad = lane >> 4;

  f32x4 acc[4][2];
#pragma unroll
  for (int i = 0; i < 4; ++i)
#pragma unroll
    for (int j = 0; j < 2; ++j) acc[i][j] = (f32x4){0.f, 0.f, 0.f, 0.f};

  for (int kt = 0; kt < KDIM; kt += 32) {
    __syncthreads();
    {  // A: 64 rows x 4 chunks = 256 chunks = 1 issue
      const int c = (w << 6) + lane;
      const int row = c >> 2;
      const int goff = ((c & 3) ^ (row & 3)) << 3;
      async16(A + (size_t)(m0 + row) * KDIM + kt + goff, A_lds + c * 8);
    }
#pragma unroll
    for (int issue = 0; issue < 2; ++issue) {  // B: 128 rows x 4 chunks = 2 issues
      const int cbase = issue * 256 + (w << 6);
      const int c = cbase + lane;
      const int row = c >> 2;
      const int goff = ((c & 3) ^ (row & 3)) << 3;
      async16(Wo + (size_t)(n0 + row) * KDIM + kt + goff, B_lds + cbase * 8);
    }
    __syncthreads();

    bf16x8 af[4], bfr[2];
#pragma unroll
    for (int i = 0; i < 4; ++i) {
      const int row = i * 16 + ln15;
      af[i] = *(const bf16x8*)&A_lds[row * 32 + ((quad ^ (row & 3)) << 3)];
    }
#pragma unroll
    for (int j = 0; j < 2; ++j) {
      const int row = (w << 5) + j * 16 + ln15;
      bfr[j] = *(const bf16x8*)&B_lds[row * 32 + ((quad ^ (row & 3)) << 3)];
    }
#pragma unroll
    for (int i = 0; i < 4; ++i)
#pragma unroll
      for (int j = 0; j < 2; ++j)
        acc[i][j] = __builtin_amdgcn_mfma_f32_16x16x32_bf16(af[i], bfr[j], acc[i][j], 0, 0, 0);
  }

  float bj2[2];
#pragma unroll
  for (int j = 0; j < 2; ++j) bj2[j] = bo[n0 + (w << 5) + j * 16 + ln15];

  __syncthreads();                          // waves done reading A/B tiles
  float* scrf = (float*)lds + (w << 9);     // per-wave 512-float scratch (2 KB)

  const int rdrow = lane & 15, rdseg = lane >> 4;
#pragma unroll
  for (int i = 0; i < 4; ++i) {
#pragma unroll
    for (int j = 0; j < 2; ++j) {
      f32x4 v;
#pragma unroll
      for (int rr = 0; rr < 4; ++rr) v[rr] = acc[i][j][rr] + bj2[j];
      *(f32x4*)&scrf[(j * 16 + ln15) * 16 + quad * 4] = v;   // col-major
    }
    const int m = m0 + i * 16 + rdrow;
    float* p = out + (size_t)m * DMODEL + n0 + (w << 5) + rdseg * 8;
#pragma unroll
    for (int cc = 0; cc < 2; ++cc) {
      f32x4 v;
#pragma unroll
      for (int e = 0; e < 4; ++e)
        v[e] = scrf[(rdseg * 8 + cc * 4 + e) * 16 + rdrow];
      *(f32x4*)&p[cc * 4] = v;
    }
  }
}

// ---------------------------------------------------------------------------
// softmax fragment build (T12): s holds S^T regs for one 32-key block
// (key = (r&3) + 8*(r>>2) + 4*hl, q = ln31). exp2 in place, then
// cvt_pk pairs + permlane32_swap reassemble the PV A-fragments entirely
// in registers — no P LDS round-trip.
// ---------------------------------------------------------------------------
__device__ __forceinline__ void softmax_frag(const f32x16& s, float& l,
                                             bf16x8& pfa, bf16x8& pfb)
{
  float p[16];
#pragma unroll
  for (int r = 0; r < 16; ++r) {
    p[r] = __builtin_amdgcn_exp2f(s[r]);
    l += p[r];
  }
  unsigned A0 = cvtpk_bf16(p[0],  p[1]);   // (0,1)   | (4,5)
  unsigned A1 = cvtpk_bf16(p[2],  p[3]);   // (2,3)   | (6,7)
  unsigned B0 = cvtpk_bf16(p[4],  p[5]);   // (8,9)   | (12,13)
  unsigned B1 = cvtpk_bf16(p[6],  p[7]);   // (10,11) | (14,15)
  unsigned C0 = cvtpk_bf16(p[8],  p[9]);   // (16,17) | (20,21)
  unsigned C1 = cvtpk_bf16(p[10], p[11]);  // (18,19) | (22,23)
  unsigned D0 = cvtpk_bf16(p[12], p[13]);  // (24,25) | (28,29)
  unsigned D1 = cvtpk_bf16(p[14], p[15]);  // (26,27) | (30,31)
  plswap(A0, B0);
  plswap(A1, B1);
  plswap(C0, D0);
  plswap(C1, D1);
  union { unsigned u[4]; bf16x8 v; } ua, ub;
  ua.u[0] = A0; ua.u[1] = A1; ua.u[2] = B0; ua.u[3] = B1;  // k 0..7 | 8..15
  ub.u[0] = C0; ub.u[1] = C1; ub.u[2] = D0; ub.u[3] = D1;  // k 16..23 | 24..31
  pfa = ua.v;
  pfb = ub.v;
}

// ---------------------------------------------------------------------------
// PV step: A-frag PF covers keys kh*64 + KS*16 + hl*8 .. +8
// ---------------------------------------------------------------------------
__device__ __forceinline__ void pvstep(const __bf16* Vs, int kh, int KS, int hl,
                                       int ln31, const bf16x8& PF,
                                       f32x16& o0, f32x16& o1)
{
  const int vchunk = (kh << 3) + 2 * KS + hl;
  bf16x8 vf0 = *(const bf16x8*)&Vs[ln31 * 128 + ((vchunk ^ (ln31 & 15)) << 3)];
  bf16x8 vf1 = *(const bf16x8*)&Vs[(32 + ln31) * 128 +
                                   ((vchunk ^ ((32 + ln31) & 15)) << 3)];
  o0 = __builtin_amdgcn_mfma_f32_32x32x16_bf16(PF, vf0, o0, 0, 0, 0);
  o1 = __builtin_amdgcn_mfma_f32_32x32x16_bf16(PF, vf1, o1, 0, 0, 0);
}

// per-128-key-sub-tile compute for one wave (its 64-key half, two 32-key
// blocks) — R1-verified serial order (R3's reorder was neutral-to-negative).
__device__ __forceinline__ void attn_tile_compute(
    const __bf16* Ks, const __bf16* Vs, const bf16x8 (&qf)[4],
    int kh, int ln31, int hl, float& l_lane, f32x16& o0, f32x16& o1)
{
#pragma unroll
  for (int half = 0; half < 2; ++half) {
    f32x16 s;
#pragma unroll
    for (int r = 0; r < 16; ++r) s[r] = 0.f;
    const int kr = (kh << 6) + half * 32 + ln31;
    __builtin_amdgcn_s_setprio(1);
#pragma unroll
    for (int ks = 0; ks < 4; ++ks) {
      bf16x8 kf = *(const bf16x8*)&Ks[kr * 64 + (((2 * ks + hl) ^ (kr & 7)) << 3)];
      s = __builtin_amdgcn_mfma_f32_32x32x16_bf16(kf, qf[ks], s, 0, 0, 0);
    }
    __builtin_amdgcn_s_setprio(0);
    bf16x8 pa, pb;
    softmax_frag(s, l_lane, pa, pb);
    __builtin_amdgcn_s_setprio(1);
    pvstep(Vs, kh, half * 2 + 0, hl, ln31, pa, o0, o1);
    pvstep(Vs, kh, half * 2 + 1, hl, ln31, pb, o0, o1);
    __builtin_amdgcn_s_setprio(0);
  }
}

// ---------------------------------------------------------------------------
// Flash attention v10 — R1 structure + 256-KEY STAGED TILES (single buffer).
// Per 256-key tile: stage two adjacent 128-key sub-tiles (K[128][64] +
// V[64][128] each, identical layout to the verified path), ONE vmcnt(0)
// drain, compute both sub-tiles. Drains/block: 16 -> 8 (the r9->r10 lever,
// which gave 1.33x, applied again). NO double-buffer (R2's failure: spill +
// scratch traffic). LDS 80 KB = Q 16 | K0 16 | K1 16 | V0 16 | V1 16 ->
// still 2 blocks/CU (grid-bound at 512 blocks anyway).
// ---------------------------------------------------------------------------
__global__ __launch_bounds__(512, 4) void attn_kernel(
    const __bf16* __restrict__ Qb, const __bf16* __restrict__ Kb,
    const __bf16* __restrict__ Vtb, __bf16* __restrict__ Ob)
{
  __shared__ __align__(16) __bf16 smem[5 * 128 * 64];   // 80 KB
  __bf16* QP = smem;            // Q tile [q128][dk64]
  __bf16* Ks = smem + 8192;     // K sub-tiles: [sub][key128][dk64]
  __bf16* Vs = smem + 24576;    // V sub-tiles: [sub][d64][key128]

  const int t = threadIdx.x, w = t >> 6, lane = t & 63;
  const int ln31 = lane & 31, hl = lane >> 5;
  const int g  = w & 3;         // q-group (32 rows of the 128-q tile)
  const int kh = w >> 2;        // key-half (64 keys) of each 128-key sub-tile
  const int bh = blockIdx.x;    // b*NHEAD + h  (XCD-locality key)
  const int q0 = blockIdx.y * 128;
  const int bb = bh >> 4, hh = bh & 15;

  const __bf16* Qg = Qb + (size_t)bh * SEQ * DKH + (size_t)q0 * DKH;
  const __bf16* Kg = Kb + (size_t)bh * SEQ * DKH;
  const __bf16* Vg = Vtb + (size_t)bh * DKH * SEQ;

  // stage Q tile (128x64 = 1024 chunks / 512 threads = 2 issues)
#pragma unroll
  for (int issue = 0; issue < 2; ++issue) {
    const int cbase = issue * 512 + (w << 6);
    const int c = cbase + lane;
    const int row = c >> 3;                         // 8 chunks per 64-elem row
    const int goff = ((c & 7) ^ (row & 7)) << 3;
    async16(Qg + (size_t)row * DKH + goff, QP + cbase * 8);
  }
  __syncthreads();

  // Q B-fragments for this wave's 32 q-rows (held in regs for whole kernel)
  const int qrow = (g << 5) + ln31;
  bf16x8 qf[4];
#pragma unroll
  for (int ks = 0; ks < 4; ++ks) {
    const int chunk = ((2 * ks + hl) ^ (qrow & 7));
    qf[ks] = *(const bf16x8*)&QP[qrow * 64 + (chunk << 3)];
  }

  float l_lane = 0.f;          // partial row-sum for q-row `qrow` (this key-half)
  f32x16 o0, o1;               // partial O[32q][64d]: d-blocks 0/1; d = db*32+ln31
#pragma unroll
  for (int r = 0; r < 16; ++r) { o0[r] = 0.f; o1[r] = 0.f; }

  for (int kt = 0; kt < SEQ; kt += 256) {
    __syncthreads();   // prior tile's Ks/Vs reads done; iter 0: Q reads done
    // stage 256 keys as two 128-key sub-tiles (compile-time sub offsets)
#pragma unroll
    for (int sub = 0; sub < 2; ++sub) {
      __bf16* Kd = Ks + sub * 8192;
      __bf16* Vd = Vs + sub * 8192;
      const int ktе_base = kt + sub * 128;
#pragma unroll
      for (int issue = 0; issue < 2; ++issue) {
        const int cbase = issue * 512 + (w << 6);
        const int c = cbase + lane;
        // K [128 keys][64 dk]: 8 chunks/row
        const int krow = c >> 3;
        const int kgoff = ((c & 7) ^ (krow & 7)) << 3;
        async16(Kg + (size_t)(ktе_base + krow) * DKH + kgoff, Kd + cbase * 8);
        // V [64 d][128 keys]: 16 chunks/row
        const int vrow = c >> 4;
        const int vgoff = ((c & 15) ^ (vrow & 15)) << 3;
        async16(Vg + (size_t)vrow * SEQ + ktе_base + vgoff, Vd + cbase * 8);
      }
    }
    __syncthreads();   // single drain per 256 keys (was per 128)

    attn_tile_compute(Ks,        Vs,        qf, kh, ln31, hl, l_lane, o0, o1);
    attn_tile_compute(Ks + 8192, Vs + 8192, qf, kh, ln31, hl, l_lane, o0, o1);
  }

  // ---- cross-wave combine: pair (w, w+4) holds same q-rows, disjoint keys.
  // Waves 4..7 dump partial O (8 KB each) + l into dead Q/K LDS; waves
  // 0..3 sum, normalize, store.
  __syncthreads();                       // all Ks/Vs LDS reads done
  float* cmb = (float*)smem;             // pair region: [d64][q32] f32
  const int dsw = ln31 & 7;
  l_lane += __shfl_xor(l_lane, 32);      // both key-sub-blocks of this wave

  if (w >= 4) {
    float* base = cmb + (g << 11);
#pragma unroll
    for (int gg = 0; gg < 4; ++gg) {
      const int qq = ((2 * gg + hl) ^ dsw) << 2;   // swizzled q-quad slot
      f32x4 va, vb;
#pragma unroll
      for (int rr = 0; rr < 4; ++rr) { va[rr] = o0[4 * gg + rr]; vb[rr] = o1[4 * gg + rr]; }
      *(f32x4*)&base[ln31 * 32 + qq]        = va;   // d = ln31
      *(f32x4*)&base[(32 + ln31) * 32 + qq] = vb;   // d = 32+ln31
    }
    if (hl == 0) cmb[8192 + (g << 5) + ln31] = l_lane;   // l region
  }
  __syncthreads();
  if (w < 4) {
    float* base = cmb + (g << 11);
#pragma unroll
    for (int gg = 0; gg < 4; ++gg) {
      const int qq = ((2 * gg + hl) ^ dsw) << 2;
      const f32x4 va = *(const f32x4*)&base[ln31 * 32 + qq];
      const f32x4 vb = *(const f32x4*)&base[(32 + ln31) * 32 + qq];
#pragma unroll
      for (int rr = 0; rr < 4; ++rr) { o0[4 * gg + rr] += va[rr]; o1[4 * gg + rr] += vb[rr]; }
    }
    const float inv = 1.0f / (l_lane + cmb[8192 + (g << 5) + ln31]);

    // epilogue: O[b, q, h*64+d]; lane = d col; fetch inv via shfl
#pragma unroll
    for (int r = 0; r < 16; ++r) {
      const int qi = (r & 3) + 8 * (r >> 2) + 4 * hl;    // q within wave's 32
      const float iq = __shfl(inv, qi);                  // from lane qi (hl=0 half)
      const int q = q0 + (g << 5) + qi;
      __bf16* rowp = Ob + ((size_t)(bb * SEQ + q)) * DMODEL + hh * DKH;
      rowp[ln31]      = (__bf16)(o0[r] * iq);
      rowp[32 + ln31] = (__bf16)(o1[r] * iq);
    }
  }
}

// ---------------------------------------------------------------------------
extern "C" void kernel_launch(void* const* d_in, const int* in_sizes, int n_in,
                              void* d_out, int out_size, void* d_ws, size_t ws_size,
                              hipStream_t stream)
{
  const float* x  = (const float*)d_in[0];
  const float* Wq = (const float*)d_in[1];
  const float* bq = (const float*)d_in[2];
  const float* Wk = (const float*)d_in[3];
  const float* bk = (const float*)d_in[4];
  const float* Wv = (const float*)d_in[5];
  const float* bv = (const float*)d_in[6];
  const float* Wo = (const float*)d_in[7];
  const float* bo = (const float*)d_in[8];
  float*  out = (float*)d_out;
  __bf16* ws  = (__bf16*)d_ws;

  // fp32 -> bf16 for x and the 4 weight matrices (one launch)
  cvt_fp32_bf16<<<dim3(2048, 5, 1), 256, 0, stream>>>(x, Wq, Wk, Wv, Wo, ws);

  // Q,K,V projections (fused, grid.z picks the matrix)
  qkv_gemm<<<dim3(MTOT / 128, DMODEL / 128, 3), 256, 0, stream>>>(
      ws + XB, ws + WQB, bq, ws + WKB, bk, ws + WVB, bv, ws);

  // flash attention: (bh, q-tile of 128) = 512 blocks x 512 threads
  attn_kernel<<<dim3(BATCH * NHEAD, SEQ / 128), 512, 0, stream>>>(
      ws + QOFF, ws + KOFF, ws + VOFF, ws + OOFF);

  // output projection -> fp32 d_out (64x128 tiles, 512 blocks)
  out_gemm<<<dim3(MTOT / 64, DMODEL / 128), 256, 0, stream>>>(
      ws + OOFF, ws + WOB, bo, out);
}